// Round 2
// 614.223 us; speedup vs baseline: 1.1494x; 1.1494x over previous
//
#include <hip/hip_runtime.h>

#define HD 256
#define NCH 64
#define NB 16
#define NPLANE (NB * NCH)           // 1024
#define NPC (NB * HD * HD)          // BN population per channel = 1048576
#define PLANE_ELEMS (HD * HD)       // 65536

typedef __attribute__((ext_vector_type(4))) float f32x4;
typedef __attribute__((ext_vector_type(8))) short s16x8;
typedef __attribute__((ext_vector_type(4))) short s16x4;

__device__ __forceinline__ short f2bf(float f) {
    unsigned u = __float_as_uint(f);
    u += 0x7FFFu + ((u >> 16) & 1u);   // round-to-nearest-even
    return (short)(u >> 16);
}
__device__ __forceinline__ float bf2f(short s) {
    return __uint_as_float(((unsigned)(unsigned short)s) << 16);
}

// LDS chunk layout: [row 0..255][64 bf16 cols], 128 B/row, XOR-swizzled:
// chunk q (8 cols) of row r lives at short index r*64 + ((q ^ (r&7))*8).
// Writes: 16 lanes = 2 rows x 8 q -> 8 banks x2 = 2-way (free).
// Reads (frag): 16 lanes = 16 rows, fixed q -> (q^(r&7)) spans 8 banks x2 (free).
__device__ __forceinline__ s16x8 ldfrag(const short* B, int row, int q) {
    return *(const s16x8*)&B[row * 64 + ((q ^ (row & 7)) << 3)];
}

// ---------------------------------------------------------------- k1: fused cvt + Gram*w (upper), raw bf16 + stats
// One block per plane. 512 thr = 8 waves. K tiled in 4 chunks of 64, double-buffered.
// Phase A: rows 0-127 x cols 0-255 (waves 2x4, 64x64 each).
// Phase B: rows 128-255 x cols 128-255 (waves 2x4, 64x32 each).
// Lower-left quadrant never computed/stored.
__global__ __launch_bounds__(512, 2) void gram_kernel(
    const float* __restrict__ x, const float* __restrict__ w,
    short* __restrict__ raw, float* __restrict__ stats)
{
    const int n    = blockIdx.x;
    const int c    = n & (NCH - 1);
    const int tid  = threadIdx.x;
    const int wid  = tid >> 6;
    const int lane = tid & 63;
    const int waveM = wid >> 2;      // 0..1
    const int waveN = wid & 3;       // 0..3
    const int lrow  = lane & 15;
    const int qlane = lane >> 4;     // 0..3

    __shared__ short As[2][16384];   // 2 x 32 KiB K-chunk buffers
    __shared__ float redS[8], redQ[8];

    const float* xp = x + (size_t)n * PLANE_ELEMS;
    const int rs = tid >> 3;         // 0..63  (row within 64-row group)
    const int qs = tid & 7;          // 0..7   (8-col group within chunk)

    f32x4 accA[4][4], accB[4][2];
    #pragma unroll
    for (int i = 0; i < 4; ++i) {
        #pragma unroll
        for (int j = 0; j < 4; ++j) accA[i][j] = (f32x4){0.f, 0.f, 0.f, 0.f};
        accB[i][0] = (f32x4){0.f, 0.f, 0.f, 0.f};
        accB[i][1] = (f32x4){0.f, 0.f, 0.f, 0.f};
    }

    f32x4 lr[4][2];

    // prologue: chunk 0 load + cvt + swizzled LDS write
    #pragma unroll
    for (int j = 0; j < 4; ++j) {
        const float* p = xp + (size_t)(j * 64 + rs) * HD + qs * 8;
        lr[j][0] = *(const f32x4*)p;
        lr[j][1] = *(const f32x4*)(p + 4);
    }
    #pragma unroll
    for (int j = 0; j < 4; ++j) {
        const int row = j * 64 + rs;
        s16x8 o = { f2bf(lr[j][0].x), f2bf(lr[j][0].y), f2bf(lr[j][0].z), f2bf(lr[j][0].w),
                    f2bf(lr[j][1].x), f2bf(lr[j][1].y), f2bf(lr[j][1].z), f2bf(lr[j][1].w) };
        *(s16x8*)&As[0][row * 64 + ((qs ^ (row & 7)) << 3)] = o;
    }

    #pragma unroll
    for (int kc = 0; kc < 4; ++kc) {
        __syncthreads();             // buf[kc&1] fully written; prev reads of buf[(kc+1)&1] done
        // T14 issue-early: next chunk's global loads in flight across the compute phase
        if (kc < 3) {
            #pragma unroll
            for (int j = 0; j < 4; ++j) {
                const float* p = xp + (size_t)(j * 64 + rs) * HD + (kc + 1) * 64 + qs * 8;
                lr[j][0] = *(const f32x4*)p;
                lr[j][1] = *(const f32x4*)(p + 4);
            }
        }
        const short* B = As[kc & 1];
        #pragma unroll
        for (int kk = 0; kk < 2; ++kk) {
            const int q = kk * 4 + qlane;
            s16x8 a0[4], b0[4];
            #pragma unroll
            for (int mi = 0; mi < 4; ++mi)
                a0[mi] = ldfrag(B, waveM * 64 + mi * 16 + lrow, q);
            #pragma unroll
            for (int ni = 0; ni < 4; ++ni)
                b0[ni] = ldfrag(B, waveN * 64 + ni * 16 + lrow, q);
            #pragma unroll
            for (int mi = 0; mi < 4; ++mi)
                #pragma unroll
                for (int ni = 0; ni < 4; ++ni)
                    accA[mi][ni] = __builtin_amdgcn_mfma_f32_16x16x32_bf16(
                        a0[mi], b0[ni], accA[mi][ni], 0, 0, 0);
            s16x8 a1[4], b1[2];
            #pragma unroll
            for (int mi = 0; mi < 4; ++mi)
                a1[mi] = ldfrag(B, 128 + waveM * 64 + mi * 16 + lrow, q);
            #pragma unroll
            for (int ni = 0; ni < 2; ++ni)
                b1[ni] = ldfrag(B, 128 + waveN * 32 + ni * 16 + lrow, q);
            #pragma unroll
            for (int mi = 0; mi < 4; ++mi)
                #pragma unroll
                for (int ni = 0; ni < 2; ++ni)
                    accB[mi][ni] = __builtin_amdgcn_mfma_f32_16x16x32_bf16(
                        a1[mi], b1[ni], accB[mi][ni], 0, 0, 0);
        }
        // write-late: cvt + LDS write of next chunk (other buffer; safe vs current readers)
        if (kc < 3) {
            #pragma unroll
            for (int j = 0; j < 4; ++j) {
                const int row = j * 64 + rs;
                s16x8 o = { f2bf(lr[j][0].x), f2bf(lr[j][0].y), f2bf(lr[j][0].z), f2bf(lr[j][0].w),
                            f2bf(lr[j][1].x), f2bf(lr[j][1].y), f2bf(lr[j][1].z), f2bf(lr[j][1].w) };
                *(s16x8*)&As[(kc + 1) & 1][row * 64 + ((qs ^ (row & 7)) << 3)] = o;
            }
        }
    }

    // epilogue: mask (k>=i), weight, store raw bf16, accumulate stats
    const float* wp = w + (size_t)c * PLANE_ELEMS;
    short* rp = raw + (size_t)n * PLANE_ELEMS;
    float lsum = 0.f, lsq = 0.f;
    const int row0 = qlane * 4;
    const int col0 = lrow;
    #pragma unroll
    for (int mi = 0; mi < 4; ++mi) {
        #pragma unroll
        for (int ni = 0; ni < 4; ++ni) {
            const int gk = waveN * 64 + ni * 16 + col0;
            #pragma unroll
            for (int r = 0; r < 4; ++r) {
                const int gi = waveM * 64 + mi * 16 + row0 + r;
                float v = accA[mi][ni][r];
                float val = (gk >= gi) ? v * wp[gi * HD + gk] : 0.f;
                lsum += val;
                lsq  += val * val;
                rp[gi * HD + gk] = f2bf(val);
            }
        }
        #pragma unroll
        for (int ni = 0; ni < 2; ++ni) {
            const int gk = 128 + waveN * 32 + ni * 16 + col0;
            #pragma unroll
            for (int r = 0; r < 4; ++r) {
                const int gi = 128 + waveM * 64 + mi * 16 + row0 + r;
                float v = accB[mi][ni][r];
                float val = (gk >= gi) ? v * wp[gi * HD + gk] : 0.f;
                lsum += val;
                lsq  += val * val;
                rp[gi * HD + gk] = f2bf(val);
            }
        }
    }

    #pragma unroll
    for (int off = 32; off > 0; off >>= 1) {
        lsum += __shfl_down(lsum, off);
        lsq  += __shfl_down(lsq, off);
    }
    if (lane == 0) { redS[wid] = lsum; redQ[wid] = lsq; }
    __syncthreads();
    if (tid == 0) {
        float s = 0.f, s2 = 0.f;
        #pragma unroll
        for (int i = 0; i < 8; ++i) { s += redS[i]; s2 += redQ[i]; }
        atomicAdd(&stats[2 * c],     s);
        atomicAdd(&stats[2 * c + 1], s2);
    }
}

// ---------------------------------------------------------------- k2: normalize (raw bf16 -> out fp32)
__global__ __launch_bounds__(256) void bn_kernel(
    const float* __restrict__ gamma, const float* __restrict__ beta,
    float* __restrict__ out, const float* __restrict__ stats,
    const short* __restrict__ raw)
{
    const int n   = blockIdx.x;     // 0..1023
    const int seg = blockIdx.y;     // 0..15
    const int tid = threadIdx.x;
    const int c   = n & (NCH - 1);

    float s  = stats[2 * c];
    float sq = stats[2 * c + 1];
    float mean = s * (1.0f / (float)NPC);
    float var  = sq * (1.0f / (float)NPC) - mean * mean;
    float rstd = rsqrtf(var + 1e-5f);
    float scale = rstd * gamma[c];
    float shift = beta[c] - mean * scale;

    const short* rp = raw + (size_t)n * PLANE_ELEMS;
    float* op = out + (size_t)n * PLANE_ELEMS;
    f32x4 cv = {shift, shift, shift, shift};

    #pragma unroll
    for (int k = 0; k < 2; ++k) {
        const int idx8 = seg * 512 + k * 256 + tid;  // 8-element unit, 8192/plane
        const int r  = idx8 >> 5;
        const int c8 = idx8 & 31;
        // fully-masked / never-written chunks -> constant, no load
        const bool cst = (r < 128) ? ((c8 * 8 + 7) < r)
                                   : (c8 < 16 || (((c8 - 16) * 8 + 7) < (r - 128)));
        float* o = &op[(size_t)idx8 * 8];
        if (cst) {
            *(f32x4*)o       = cv;
            *(f32x4*)(o + 4) = cv;
        } else {
            s16x8 v = *(const s16x8*)&rp[(size_t)idx8 * 8];
            f32x4 lo = { bf2f(v[0]) * scale + shift, bf2f(v[1]) * scale + shift,
                         bf2f(v[2]) * scale + shift, bf2f(v[3]) * scale + shift };
            f32x4 hi = { bf2f(v[4]) * scale + shift, bf2f(v[5]) * scale + shift,
                         bf2f(v[6]) * scale + shift, bf2f(v[7]) * scale + shift };
            *(f32x4*)o       = lo;
            *(f32x4*)(o + 4) = hi;
        }
    }
}

// ---------------------------------------------------------------- fallback (no big workspace; fp32 staging, 2-pass)
template <int PASS>
__global__ __launch_bounds__(256) void gram_bn_fb(
    const float* __restrict__ x, const float* __restrict__ w,
    const float* __restrict__ gamma, const float* __restrict__ beta,
    float* __restrict__ out, float* __restrict__ stats)
{
    const int tile = blockIdx.x;
    const int b    = blockIdx.y;
    const int c    = blockIdx.z;
    const int n    = b * NCH + c;
    const int tid  = threadIdx.x;

    float mean = 0.f, rstd = 0.f, gm = 0.f, bt = 0.f;
    if (PASS == 1) {
        float s  = stats[2*c];
        float sq = stats[2*c+1];
        mean = s * (1.0f / (float)NPC);
        float var = sq * (1.0f / (float)NPC) - mean * mean;
        rstd = rsqrtf(var + 1e-5f);
        gm = gamma[c]; bt = beta[c];
    }
    if (PASS == 1 && tile == 3) {
        float v = (0.f - mean) * rstd * gm + bt;
        f32x4 vv = {v, v, v, v};
        float* op = out + (size_t)n * PLANE_ELEMS;
        for (int it = 0; it < 16; ++it) {
            int t  = it * 256 + tid;
            int r  = t >> 5;
            int c4 = (t & 31) * 4;
            *(f32x4*)&op[(size_t)(128 + r) * HD + c4] = vv;
        }
        return;
    }
    int ti, tk;
    if      (tile == 0) { ti = 0; tk = 0; }
    else if (tile == 1) { ti = 0; tk = 1; }
    else                { ti = 1; tk = 1; }
    const float* xp = x + (size_t)n * PLANE_ELEMS;
    __shared__ short As[128 * 40];
    __shared__ short Bs[128 * 40];
    __shared__ float red[512];
    const int wid   = tid >> 6;
    const int lane  = tid & 63;
    const int waveM = wid >> 1, waveN = wid & 1;
    const int lrow  = lane & 15;
    const int lkk   = (lane >> 4) * 8;
    f32x4 acc[4][4];
    for (int i = 0; i < 4; ++i)
        for (int j = 0; j < 4; ++j)
            acc[i][j] = (f32x4){0.f, 0.f, 0.f, 0.f};
    const int rr = tid >> 3;
    const int cc = (tid & 7) * 4;
    for (int kb = 0; kb < 8; ++kb) {
        for (int it = 0; it < 4; ++it) {
            int r = rr + it * 32;
            f32x4 av = *(const f32x4*)&xp[(size_t)(ti*128 + r) * HD + kb*32 + cc];
            f32x4 bv = *(const f32x4*)&xp[(size_t)(tk*128 + r) * HD + kb*32 + cc];
            s16x4 a4 = { f2bf(av.x), f2bf(av.y), f2bf(av.z), f2bf(av.w) };
            s16x4 b4 = { f2bf(bv.x), f2bf(bv.y), f2bf(bv.z), f2bf(bv.w) };
            *(s16x4*)&As[r*40 + cc] = a4;
            *(s16x4*)&Bs[r*40 + cc] = b4;
        }
        __syncthreads();
        s16x8 af[4], bfr[4];
        for (int mi = 0; mi < 4; ++mi)
            af[mi]  = *(s16x8*)&As[(waveM*64 + mi*16 + lrow)*40 + lkk];
        for (int ni = 0; ni < 4; ++ni)
            bfr[ni] = *(s16x8*)&Bs[(waveN*64 + ni*16 + lrow)*40 + lkk];
        for (int mi = 0; mi < 4; ++mi)
            for (int ni = 0; ni < 4; ++ni)
                acc[mi][ni] = __builtin_amdgcn_mfma_f32_16x16x32_bf16(
                    af[mi], bfr[ni], acc[mi][ni], 0, 0, 0);
        __syncthreads();
    }
    float lsum = 0.f, lsq = 0.f;
    const int row0 = (lane >> 4) * 4;
    const int col0 = lane & 15;
    for (int mi = 0; mi < 4; ++mi) {
        for (int ni = 0; ni < 4; ++ni) {
            int gk = tk*128 + waveN*64 + ni*16 + col0;
            for (int r = 0; r < 4; ++r) {
                int gi = ti*128 + waveM*64 + mi*16 + row0 + r;
                float v = acc[mi][ni][r];
                float val = (gk >= gi)
                    ? v * w[(size_t)c * PLANE_ELEMS + (size_t)gi * HD + gk]
                    : 0.f;
                if (PASS == 0) { lsum += val; lsq += val * val; }
                else out[(size_t)n * PLANE_ELEMS + (size_t)gi * HD + gk] =
                        (val - mean) * rstd * gm + bt;
            }
        }
    }
    if (PASS == 0) {
        red[tid] = lsum; red[256 + tid] = lsq;
        __syncthreads();
        for (int s = 128; s > 0; s >>= 1) {
            if (tid < s) { red[tid] += red[tid+s]; red[256+tid] += red[256+tid+s]; }
            __syncthreads();
        }
        if (tid == 0) {
            atomicAdd(&stats[2*c],     red[0]);
            atomicAdd(&stats[2*c + 1], red[256]);
        }
    }
}

extern "C" void kernel_launch(void* const* d_in, const int* in_sizes, int n_in,
                              void* d_out, int out_size, void* d_ws, size_t ws_size,
                              hipStream_t stream) {
    const float* x     = (const float*)d_in[0];
    const float* w     = (const float*)d_in[1];
    const float* gamma = (const float*)d_in[2];
    const float* beta  = (const float*)d_in[3];
    float* out   = (float*)d_out;
    float* stats = (float*)d_ws;

    hipMemsetAsync(d_ws, 0, 128 * sizeof(float), stream);

    const size_t raw_bytes = (size_t)NPLANE * PLANE_ELEMS * sizeof(short); // 128 MiB
    if (ws_size >= 1024 + raw_bytes) {
        short* raw = (short*)((char*)d_ws + 1024);
        gram_kernel<<<dim3(NPLANE), dim3(512), 0, stream>>>(x, w, raw, stats);
        bn_kernel<<<dim3(NPLANE, 16), dim3(256), 0, stream>>>(gamma, beta, out, stats, raw);
    } else {
        gram_bn_fb<0><<<dim3(3, NB, NCH), dim3(256), 0, stream>>>(x, w, gamma, beta, out, stats);
        gram_bn_fb<1><<<dim3(4, NB, NCH), dim3(256), 0, stream>>>(x, w, gamma, beta, out, stats);
    }
}

// Round 3
// 599.564 us; speedup vs baseline: 1.1775x; 1.0244x over previous
//
#include <hip/hip_runtime.h>

#define HD 256
#define NCH 64
#define NB 16
#define NPLANE (NB * NCH)           // 1024
#define NPC (NB * HD * HD)          // BN population per channel = 1048576
#define PLANE_ELEMS (HD * HD)       // 65536

typedef __attribute__((ext_vector_type(4))) float f32x4;
typedef __attribute__((ext_vector_type(8))) short s16x8;
typedef __attribute__((ext_vector_type(4))) short s16x4;

__device__ __forceinline__ short f2bf(float f) {
    unsigned u = __float_as_uint(f);
    u += 0x7FFFu + ((u >> 16) & 1u);   // round-to-nearest-even
    return (short)(u >> 16);
}
__device__ __forceinline__ float bf2f(short s) {
    return __uint_as_float(((unsigned)(unsigned short)s) << 16);
}

// LDS tile: [128 rows][64 bf16 cols], 128 B/row, XOR-swizzled:
// 8-col chunk q of row r lives at short index r*64 + ((q ^ (r&7))*8).
// Write: 8 qs lanes/row -> permutation of 8 slots (32 banks once). Free.
// Read (frag): 16 rows, fixed q -> slots q^(r&7) hit each bank exactly 2x. Free.
__device__ __forceinline__ s16x8 ldfrag64(const short* B, int row, int q) {
    return *(const s16x8*)&B[row * 64 + ((q ^ (row & 7)) << 3)];
}

// ---------------------------------------------------------------- k1: fused cvt + Gram*w tile, raw bf16 + stats
// Grid (3, NB, NCH): tile 0:T00(diag) 1:T01 2:T11(diag). 512 thr = 8 waves (2x4),
// each wave owns 64x32 of the 128x128 tile -> acc = 32 AGPR; total regs ~110
// -> __launch_bounds__(512,4) -> 2 blocks/CU resident (vs 1 for the fused version).
// K in 4 chunks of 64, double-buffered, issue-early / write-late staging.
__global__ __launch_bounds__(512, 4) void gram_kernel(
    const float* __restrict__ x, const float* __restrict__ w,
    short* __restrict__ raw, float* __restrict__ stats)
{
    const int tile = blockIdx.x;
    const int ti = (tile == 2) ? 1 : 0;
    const int tk = (tile == 0) ? 0 : 1;
    const bool diag = (ti == tk);
    const int b = blockIdx.y;
    const int c = blockIdx.z;
    const int n = b * NCH + c;
    const int tid = threadIdx.x;
    const int wid = tid >> 6, lane = tid & 63;
    const int waveM = wid >> 2;      // 0..1 -> 64-row half
    const int waveN = wid & 3;       // 0..3 -> 32-col quarter
    const int lrow = lane & 15;
    const int qlane = lane >> 4;     // 0..3

    __shared__ short As[2][8192];    // 2 x 16 KiB (128 rows x 64 cols bf16)
    __shared__ short Bs[2][8192];
    __shared__ float redS[8], redQ[8];

    const float* xpA = x + (size_t)n * PLANE_ELEMS + (size_t)(ti * 128) * HD;
    const float* xpB = x + (size_t)n * PLANE_ELEMS + (size_t)(tk * 128) * HD;

    const int rs = tid >> 3;         // 0..63 (row within 64-row group)
    const int qs = tid & 7;          // 0..7  (8-col group within chunk)

    f32x4 acc[4][2];
    #pragma unroll
    for (int i = 0; i < 4; ++i) {
        acc[i][0] = (f32x4){0.f, 0.f, 0.f, 0.f};
        acc[i][1] = (f32x4){0.f, 0.f, 0.f, 0.f};
    }

    f32x4 lA[2][2], lB[2][2];

    // prologue: chunk 0 loads + cvt + swizzled LDS writes
    #pragma unroll
    for (int j = 0; j < 2; ++j) {
        const float* pA = xpA + (size_t)(j * 64 + rs) * HD + qs * 8;
        lA[j][0] = *(const f32x4*)pA;
        lA[j][1] = *(const f32x4*)(pA + 4);
        if (!diag) {
            const float* pB = xpB + (size_t)(j * 64 + rs) * HD + qs * 8;
            lB[j][0] = *(const f32x4*)pB;
            lB[j][1] = *(const f32x4*)(pB + 4);
        }
    }
    #pragma unroll
    for (int j = 0; j < 2; ++j) {
        const int row = j * 64 + rs;
        const int off = row * 64 + ((qs ^ (row & 7)) << 3);
        s16x8 oa = { f2bf(lA[j][0].x), f2bf(lA[j][0].y), f2bf(lA[j][0].z), f2bf(lA[j][0].w),
                     f2bf(lA[j][1].x), f2bf(lA[j][1].y), f2bf(lA[j][1].z), f2bf(lA[j][1].w) };
        *(s16x8*)&As[0][off] = oa;
        if (!diag) {
            s16x8 ob = { f2bf(lB[j][0].x), f2bf(lB[j][0].y), f2bf(lB[j][0].z), f2bf(lB[j][0].w),
                         f2bf(lB[j][1].x), f2bf(lB[j][1].y), f2bf(lB[j][1].z), f2bf(lB[j][1].w) };
            *(s16x8*)&Bs[0][off] = ob;
        }
    }

    #pragma unroll
    for (int kc = 0; kc < 4; ++kc) {
        __syncthreads();             // buf[kc&1] written; prior reads of buf[(kc+1)&1] done
        // issue-early: next chunk's global loads stay in flight across the MFMA phase
        if (kc < 3) {
            #pragma unroll
            for (int j = 0; j < 2; ++j) {
                const float* pA = xpA + (size_t)(j * 64 + rs) * HD + (kc + 1) * 64 + qs * 8;
                lA[j][0] = *(const f32x4*)pA;
                lA[j][1] = *(const f32x4*)(pA + 4);
                if (!diag) {
                    const float* pB = xpB + (size_t)(j * 64 + rs) * HD + (kc + 1) * 64 + qs * 8;
                    lB[j][0] = *(const f32x4*)pB;
                    lB[j][1] = *(const f32x4*)(pB + 4);
                }
            }
        }
        const short* Ab = As[kc & 1];
        const short* Bb = diag ? Ab : Bs[kc & 1];
        #pragma unroll
        for (int kk = 0; kk < 2; ++kk) {
            const int q = kk * 4 + qlane;
            s16x8 af[4], bf[2];
            #pragma unroll
            for (int mi = 0; mi < 4; ++mi)
                af[mi] = ldfrag64(Ab, waveM * 64 + mi * 16 + lrow, q);
            #pragma unroll
            for (int ni = 0; ni < 2; ++ni)
                bf[ni] = ldfrag64(Bb, waveN * 32 + ni * 16 + lrow, q);
            #pragma unroll
            for (int mi = 0; mi < 4; ++mi)
                #pragma unroll
                for (int ni = 0; ni < 2; ++ni)
                    acc[mi][ni] = __builtin_amdgcn_mfma_f32_16x16x32_bf16(
                        af[mi], bf[ni], acc[mi][ni], 0, 0, 0);
        }
        // write-late: cvt + LDS write of next chunk (other buffer)
        if (kc < 3) {
            #pragma unroll
            for (int j = 0; j < 2; ++j) {
                const int row = j * 64 + rs;
                const int off = row * 64 + ((qs ^ (row & 7)) << 3);
                s16x8 oa = { f2bf(lA[j][0].x), f2bf(lA[j][0].y), f2bf(lA[j][0].z), f2bf(lA[j][0].w),
                             f2bf(lA[j][1].x), f2bf(lA[j][1].y), f2bf(lA[j][1].z), f2bf(lA[j][1].w) };
                *(s16x8*)&As[(kc + 1) & 1][off] = oa;
                if (!diag) {
                    s16x8 ob = { f2bf(lB[j][0].x), f2bf(lB[j][0].y), f2bf(lB[j][0].z), f2bf(lB[j][0].w),
                                 f2bf(lB[j][1].x), f2bf(lB[j][1].y), f2bf(lB[j][1].z), f2bf(lB[j][1].w) };
                    *(s16x8*)&Bs[(kc + 1) & 1][off] = ob;
                }
            }
        }
    }

    // epilogue: mask (k>=i), weight, store raw bf16, accumulate stats
    const float* wp = w + (size_t)c * PLANE_ELEMS;
    short* rp = raw + (size_t)n * PLANE_ELEMS;
    float lsum = 0.f, lsq = 0.f;
    const int row0 = qlane * 4;
    const int col0 = lrow;
    #pragma unroll
    for (int mi = 0; mi < 4; ++mi) {
        #pragma unroll
        for (int ni = 0; ni < 2; ++ni) {
            const int gk = tk * 128 + waveN * 32 + ni * 16 + col0;
            #pragma unroll
            for (int r = 0; r < 4; ++r) {
                const int gi = ti * 128 + waveM * 64 + mi * 16 + row0 + r;
                const bool keep = diag ? (gk >= gi) : true;   // T01: gk>=128>gi always
                float v = acc[mi][ni][r];
                float val = keep ? v * wp[gi * HD + gk] : 0.f;
                lsum += val;
                lsq  += val * val;
                rp[gi * HD + gk] = f2bf(val);
            }
        }
    }

    #pragma unroll
    for (int off = 32; off > 0; off >>= 1) {
        lsum += __shfl_down(lsum, off);
        lsq  += __shfl_down(lsq, off);
    }
    if (lane == 0) { redS[wid] = lsum; redQ[wid] = lsq; }
    __syncthreads();
    if (tid == 0) {
        float s = 0.f, s2 = 0.f;
        #pragma unroll
        for (int i = 0; i < 8; ++i) { s += redS[i]; s2 += redQ[i]; }
        atomicAdd(&stats[2 * c],     s);
        atomicAdd(&stats[2 * c + 1], s2);
    }
}

// ---------------------------------------------------------------- k2: normalize (raw bf16 -> out fp32)
__global__ __launch_bounds__(256) void bn_kernel(
    const float* __restrict__ gamma, const float* __restrict__ beta,
    float* __restrict__ out, const float* __restrict__ stats,
    const short* __restrict__ raw)
{
    const int n   = blockIdx.x;     // 0..1023
    const int seg = blockIdx.y;     // 0..15
    const int tid = threadIdx.x;
    const int c   = n & (NCH - 1);

    float s  = stats[2 * c];
    float sq = stats[2 * c + 1];
    float mean = s * (1.0f / (float)NPC);
    float var  = sq * (1.0f / (float)NPC) - mean * mean;
    float rstd = rsqrtf(var + 1e-5f);
    float scale = rstd * gamma[c];
    float shift = beta[c] - mean * scale;

    const short* rp = raw + (size_t)n * PLANE_ELEMS;
    float* op = out + (size_t)n * PLANE_ELEMS;
    f32x4 cv = {shift, shift, shift, shift};

    #pragma unroll
    for (int k = 0; k < 2; ++k) {
        const int idx8 = seg * 512 + k * 256 + tid;  // 8-element unit, 8192/plane
        const int r  = idx8 >> 5;
        const int c8 = idx8 & 31;
        // fully-masked / never-written chunks -> constant, no load
        const bool cst = (r < 128) ? ((c8 * 8 + 7) < r)
                                   : (c8 < 16 || (((c8 - 16) * 8 + 7) < (r - 128)));
        float* o = &op[(size_t)idx8 * 8];
        if (cst) {
            *(f32x4*)o       = cv;
            *(f32x4*)(o + 4) = cv;
        } else {
            s16x8 v = *(const s16x8*)&rp[(size_t)idx8 * 8];
            f32x4 lo = { bf2f(v[0]) * scale + shift, bf2f(v[1]) * scale + shift,
                         bf2f(v[2]) * scale + shift, bf2f(v[3]) * scale + shift };
            f32x4 hi = { bf2f(v[4]) * scale + shift, bf2f(v[5]) * scale + shift,
                         bf2f(v[6]) * scale + shift, bf2f(v[7]) * scale + shift };
            *(f32x4*)o       = lo;
            *(f32x4*)(o + 4) = hi;
        }
    }
}

// ---------------------------------------------------------------- fallback (no big workspace; fp32 staging, 2-pass)
template <int PASS>
__global__ __launch_bounds__(256) void gram_bn_fb(
    const float* __restrict__ x, const float* __restrict__ w,
    const float* __restrict__ gamma, const float* __restrict__ beta,
    float* __restrict__ out, float* __restrict__ stats)
{
    const int tile = blockIdx.x;
    const int b    = blockIdx.y;
    const int c    = blockIdx.z;
    const int n    = b * NCH + c;
    const int tid  = threadIdx.x;

    float mean = 0.f, rstd = 0.f, gm = 0.f, bt = 0.f;
    if (PASS == 1) {
        float s  = stats[2*c];
        float sq = stats[2*c+1];
        mean = s * (1.0f / (float)NPC);
        float var = sq * (1.0f / (float)NPC) - mean * mean;
        rstd = rsqrtf(var + 1e-5f);
        gm = gamma[c]; bt = beta[c];
    }
    if (PASS == 1 && tile == 3) {
        float v = (0.f - mean) * rstd * gm + bt;
        f32x4 vv = {v, v, v, v};
        float* op = out + (size_t)n * PLANE_ELEMS;
        for (int it = 0; it < 16; ++it) {
            int t  = it * 256 + tid;
            int r  = t >> 5;
            int c4 = (t & 31) * 4;
            *(f32x4*)&op[(size_t)(128 + r) * HD + c4] = vv;
        }
        return;
    }
    int ti, tk;
    if      (tile == 0) { ti = 0; tk = 0; }
    else if (tile == 1) { ti = 0; tk = 1; }
    else                { ti = 1; tk = 1; }
    const float* xp = x + (size_t)n * PLANE_ELEMS;
    __shared__ short As[128 * 40];
    __shared__ short Bs[128 * 40];
    __shared__ float red[512];
    const int wid   = tid >> 6;
    const int lane  = tid & 63;
    const int waveM = wid >> 1, waveN = wid & 1;
    const int lrow  = lane & 15;
    const int lkk   = (lane >> 4) * 8;
    f32x4 acc[4][4];
    for (int i = 0; i < 4; ++i)
        for (int j = 0; j < 4; ++j)
            acc[i][j] = (f32x4){0.f, 0.f, 0.f, 0.f};
    const int rr = tid >> 3;
    const int cc = (tid & 7) * 4;
    for (int kb = 0; kb < 8; ++kb) {
        for (int it = 0; it < 4; ++it) {
            int r = rr + it * 32;
            f32x4 av = *(const f32x4*)&xp[(size_t)(ti*128 + r) * HD + kb*32 + cc];
            f32x4 bv = *(const f32x4*)&xp[(size_t)(tk*128 + r) * HD + kb*32 + cc];
            s16x4 a4 = { f2bf(av.x), f2bf(av.y), f2bf(av.z), f2bf(av.w) };
            s16x4 b4 = { f2bf(bv.x), f2bf(bv.y), f2bf(bv.z), f2bf(bv.w) };
            *(s16x4*)&As[r*40 + cc] = a4;
            *(s16x4*)&Bs[r*40 + cc] = b4;
        }
        __syncthreads();
        s16x8 af[4], bfr[4];
        for (int mi = 0; mi < 4; ++mi)
            af[mi]  = *(s16x8*)&As[(waveM*64 + mi*16 + lrow)*40 + lkk];
        for (int ni = 0; ni < 4; ++ni)
            bfr[ni] = *(s16x8*)&Bs[(waveN*64 + ni*16 + lrow)*40 + lkk];
        for (int mi = 0; mi < 4; ++mi)
            for (int ni = 0; ni < 4; ++ni)
                acc[mi][ni] = __builtin_amdgcn_mfma_f32_16x16x32_bf16(
                    af[mi], bfr[ni], acc[mi][ni], 0, 0, 0);
        __syncthreads();
    }
    float lsum = 0.f, lsq = 0.f;
    const int row0 = (lane >> 4) * 4;
    const int col0 = lane & 15;
    for (int mi = 0; mi < 4; ++mi) {
        for (int ni = 0; ni < 4; ++ni) {
            int gk = tk*128 + waveN*64 + ni*16 + col0;
            for (int r = 0; r < 4; ++r) {
                int gi = ti*128 + waveM*64 + mi*16 + row0 + r;
                float v = acc[mi][ni][r];
                float val = (gk >= gi)
                    ? v * w[(size_t)c * PLANE_ELEMS + (size_t)gi * HD + gk]
                    : 0.f;
                if (PASS == 0) { lsum += val; lsq += val * val; }
                else out[(size_t)n * PLANE_ELEMS + (size_t)gi * HD + gk] =
                        (val - mean) * rstd * gm + bt;
            }
        }
    }
    if (PASS == 0) {
        red[tid] = lsum; red[256 + tid] = lsq;
        __syncthreads();
        for (int s = 128; s > 0; s >>= 1) {
            if (tid < s) { red[tid] += red[tid+s]; red[256+tid] += red[256+tid+s]; }
            __syncthreads();
        }
        if (tid == 0) {
            atomicAdd(&stats[2*c],     red[0]);
            atomicAdd(&stats[2*c + 1], red[256]);
        }
    }
}

extern "C" void kernel_launch(void* const* d_in, const int* in_sizes, int n_in,
                              void* d_out, int out_size, void* d_ws, size_t ws_size,
                              hipStream_t stream) {
    const float* x     = (const float*)d_in[0];
    const float* w     = (const float*)d_in[1];
    const float* gamma = (const float*)d_in[2];
    const float* beta  = (const float*)d_in[3];
    float* out   = (float*)d_out;
    float* stats = (float*)d_ws;

    hipMemsetAsync(d_ws, 0, 128 * sizeof(float), stream);

    const size_t raw_bytes = (size_t)NPLANE * PLANE_ELEMS * sizeof(short); // 128 MiB
    if (ws_size >= 1024 + raw_bytes) {
        short* raw = (short*)((char*)d_ws + 1024);
        gram_kernel<<<dim3(3, NB, NCH), dim3(512), 0, stream>>>(x, w, raw, stats);
        bn_kernel<<<dim3(NPLANE, 16), dim3(256), 0, stream>>>(gamma, beta, out, stats, raw);
    } else {
        gram_bn_fb<0><<<dim3(3, NB, NCH), dim3(256), 0, stream>>>(x, w, gamma, beta, out, stats);
        gram_bn_fb<1><<<dim3(4, NB, NCH), dim3(256), 0, stream>>>(x, w, gamma, beta, out, stats);
    }
}

// Round 4
// 594.935 us; speedup vs baseline: 1.1867x; 1.0078x over previous
//
#include <hip/hip_runtime.h>

#define HD 256
#define NCH 64
#define NB 16
#define NPLANE (NB * NCH)           // 1024
#define NPC (NB * HD * HD)          // BN population per channel = 1048576
#define PLANE_ELEMS (HD * HD)       // 65536

typedef __attribute__((ext_vector_type(4))) float f32x4;
typedef __attribute__((ext_vector_type(8))) short s16x8;
typedef __attribute__((ext_vector_type(4))) short s16x4;

__device__ __forceinline__ short f2bf(float f) {
    unsigned u = __float_as_uint(f);
    u += 0x7FFFu + ((u >> 16) & 1u);   // round-to-nearest-even
    return (short)(u >> 16);
}
__device__ __forceinline__ float bf2f(short s) {
    return __uint_as_float(((unsigned)(unsigned short)s) << 16);
}

// LDS tile: [64 rows][64 bf16 cols], 128 B/row, XOR-swizzled (same scheme as the
// measured-0-conflict round-3 kernel): 8-col unit q of row r at r*64 + ((q^(r&7))*8).
__device__ __forceinline__ s16x8 ldfrag64(const short* B, int row, int q) {
    return *(const s16x8*)&B[row * 64 + ((q ^ (row & 7)) << 3)];
}
__device__ __forceinline__ void wr_lds(short* buf, int row, int qs,
                                       const f32x4& a, const f32x4& b) {
    s16x8 o = { f2bf(a.x), f2bf(a.y), f2bf(a.z), f2bf(a.w),
                f2bf(b.x), f2bf(b.y), f2bf(b.z), f2bf(b.w) };
    *(s16x8*)&buf[row * 64 + ((qs ^ (row & 7)) << 3)] = o;
}

// ---------------------------------------------------------------- k1: fused cvt + Gram*w, raw bf16 + stats
// 64x64 upper-triangle tiles: 10 per plane (t: (I,J), I<=J), grid 10240 = 8*1280.
// XCD-grouped remap: all 10 tiles of a plane run consecutively on ONE XCD -> L2 reuse of x rows.
// 256 thr = 4 waves (2x2 of 32x32, acc 16 regs). Single LDS buffer (16.4 KB) -> 4 blocks/CU.
// 2-deep pipeline: loads for chunk k+2 issued while chunk k computes (parity reg sets).
__global__ __launch_bounds__(256, 4) void gram_kernel(
    const float* __restrict__ x, const float* __restrict__ w,
    short* __restrict__ raw, float* __restrict__ stats)
{
    const int bid = blockIdx.x;
    const int wk  = (bid & 7) * 1280 + (bid >> 3);    // bijective XCD grouping
    const int plane = wk / 10;                        // 0..1023
    const int t = wk - plane * 10;                    // 0..9 upper-tri tile id
    const int I = (t < 4) ? 0 : (t < 7) ? 1 : (t < 9) ? 2 : 3;
    const int J = t - ((I == 0) ? 0 : (I == 1) ? 4 : (I == 2) ? 7 : 9) + I;
    const bool diag = (I == J);
    const int c = plane & (NCH - 1);
    const int tid = threadIdx.x;
    const int wid = tid >> 6, lane = tid & 63;
    const int wm = wid >> 1, wn = wid & 1;            // 2x2 wave grid, 32x32 each
    const int lrow = lane & 15, qlane = lane >> 4;

    __shared__ short As[4096];        // 64x64 bf16, 8 KiB
    __shared__ short Bs[4096];
    __shared__ float redS[4], redQ[4];

    const float* xpA = x + (size_t)plane * PLANE_ELEMS + (size_t)(I * 64) * HD;
    const float* xpB = x + (size_t)plane * PLANE_ELEMS + (size_t)(J * 64) * HD;
    const int r0 = tid >> 3;          // 0..31: rows r0, r0+32
    const int qs = tid & 7;           // 8-col unit within 64-col chunk

    f32x4 acc[2][2];
    #pragma unroll
    for (int i = 0; i < 2; ++i)
        #pragma unroll
        for (int j = 0; j < 2; ++j)
            acc[i][j] = (f32x4){0.f, 0.f, 0.f, 0.f};

    // parity staging sets: [set][row-j*2 + half]
    f32x4 sA[2][4], sB[2][4];

    // prologue: issue chunks 0 and 1 (2-deep)
    #pragma unroll
    for (int kc = 0; kc < 2; ++kc) {
        #pragma unroll
        for (int j = 0; j < 2; ++j) {
            const float* p = xpA + (size_t)(j * 32 + r0) * HD + kc * 64 + qs * 8;
            sA[kc][j * 2]     = *(const f32x4*)p;
            sA[kc][j * 2 + 1] = *(const f32x4*)(p + 4);
            if (!diag) {
                const float* pb = xpB + (size_t)(j * 32 + r0) * HD + kc * 64 + qs * 8;
                sB[kc][j * 2]     = *(const f32x4*)pb;
                sB[kc][j * 2 + 1] = *(const f32x4*)(pb + 4);
            }
        }
    }

    #pragma unroll
    for (int kc = 0; kc < 4; ++kc) {
        const int st = kc & 1;
        if (kc > 0) __syncthreads();  // all waves done reading previous chunk
        // write-late: this chunk's staged regs -> LDS (vmcnt waits on loads issued 2 phases ago)
        #pragma unroll
        for (int j = 0; j < 2; ++j) {
            wr_lds(As, j * 32 + r0, qs, sA[st][j * 2], sA[st][j * 2 + 1]);
            if (!diag)
                wr_lds(Bs, j * 32 + r0, qs, sB[st][j * 2], sB[st][j * 2 + 1]);
        }
        // issue-early: chunk kc+2 loads into the set just freed
        if (kc < 2) {
            #pragma unroll
            for (int j = 0; j < 2; ++j) {
                const float* p = xpA + (size_t)(j * 32 + r0) * HD + (kc + 2) * 64 + qs * 8;
                sA[st][j * 2]     = *(const f32x4*)p;
                sA[st][j * 2 + 1] = *(const f32x4*)(p + 4);
                if (!diag) {
                    const float* pb = xpB + (size_t)(j * 32 + r0) * HD + (kc + 2) * 64 + qs * 8;
                    sB[st][j * 2]     = *(const f32x4*)pb;
                    sB[st][j * 2 + 1] = *(const f32x4*)(pb + 4);
                }
            }
        }
        __syncthreads();              // LDS visible
        const short* Bsrc = diag ? As : Bs;
        #pragma unroll
        for (int kk = 0; kk < 2; ++kk) {
            const int q = kk * 4 + qlane;
            s16x8 af0 = ldfrag64(As,   wm * 32 +      lrow, q);
            s16x8 af1 = ldfrag64(As,   wm * 32 + 16 + lrow, q);
            s16x8 bf0 = ldfrag64(Bsrc, wn * 32 +      lrow, q);
            s16x8 bf1 = ldfrag64(Bsrc, wn * 32 + 16 + lrow, q);
            acc[0][0] = __builtin_amdgcn_mfma_f32_16x16x32_bf16(af0, bf0, acc[0][0], 0, 0, 0);
            acc[0][1] = __builtin_amdgcn_mfma_f32_16x16x32_bf16(af0, bf1, acc[0][1], 0, 0, 0);
            acc[1][0] = __builtin_amdgcn_mfma_f32_16x16x32_bf16(af1, bf0, acc[1][0], 0, 0, 0);
            acc[1][1] = __builtin_amdgcn_mfma_f32_16x16x32_bf16(af1, bf1, acc[1][1], 0, 0, 0);
        }
    }

    // epilogue: mask (k>=i, diag tiles only), weight, store raw bf16, accumulate stats
    const float* wp = w + (size_t)c * PLANE_ELEMS;
    short* rp = raw + (size_t)plane * PLANE_ELEMS;
    float lsum = 0.f, lsq = 0.f;
    #pragma unroll
    for (int mi = 0; mi < 2; ++mi) {
        #pragma unroll
        for (int ni = 0; ni < 2; ++ni) {
            const int gk = J * 64 + wn * 32 + ni * 16 + lrow;
            #pragma unroll
            for (int r = 0; r < 4; ++r) {
                const int gi = I * 64 + wm * 32 + mi * 16 + qlane * 4 + r;
                const bool keep = diag ? (gk >= gi) : true;
                float v = acc[mi][ni][r];
                float val = keep ? v * wp[gi * HD + gk] : 0.f;
                lsum += val;
                lsq  += val * val;
                rp[gi * HD + gk] = f2bf(val);
            }
        }
    }

    #pragma unroll
    for (int off = 32; off > 0; off >>= 1) {
        lsum += __shfl_down(lsum, off);
        lsq  += __shfl_down(lsq, off);
    }
    if (lane == 0) { redS[wid] = lsum; redQ[wid] = lsq; }
    __syncthreads();
    if (tid == 0) {
        float s = redS[0] + redS[1] + redS[2] + redS[3];
        float s2 = redQ[0] + redQ[1] + redQ[2] + redQ[3];
        atomicAdd(&stats[2 * c],     s);
        atomicAdd(&stats[2 * c + 1], s2);
    }
}

// ---------------------------------------------------------------- k2: normalize (raw bf16 -> out fp32)
__global__ __launch_bounds__(256) void bn_kernel(
    const float* __restrict__ gamma, const float* __restrict__ beta,
    float* __restrict__ out, const float* __restrict__ stats,
    const short* __restrict__ raw)
{
    const int n   = blockIdx.x;     // 0..1023
    const int seg = blockIdx.y;     // 0..15
    const int tid = threadIdx.x;
    const int c   = n & (NCH - 1);

    float s  = stats[2 * c];
    float sq = stats[2 * c + 1];
    float mean = s * (1.0f / (float)NPC);
    float var  = sq * (1.0f / (float)NPC) - mean * mean;
    float rstd = rsqrtf(var + 1e-5f);
    float scale = rstd * gamma[c];
    float shift = beta[c] - mean * scale;

    const short* rp = raw + (size_t)n * PLANE_ELEMS;
    float* op = out + (size_t)n * PLANE_ELEMS;
    f32x4 cv = {shift, shift, shift, shift};

    #pragma unroll
    for (int k = 0; k < 2; ++k) {
        const int idx8 = seg * 512 + k * 256 + tid;  // 8-element unit, 8192/plane
        const int r  = idx8 >> 5;
        const int c8 = idx8 & 31;
        // fully-below-diagonal units: constant, no load (covers unwritten I>J tiles too)
        const bool cst = (c8 * 8 + 7) < r;
        float* o = &op[(size_t)idx8 * 8];
        if (cst) {
            *(f32x4*)o       = cv;
            *(f32x4*)(o + 4) = cv;
        } else {
            s16x8 v = *(const s16x8*)&rp[(size_t)idx8 * 8];
            f32x4 lo = { bf2f(v[0]) * scale + shift, bf2f(v[1]) * scale + shift,
                         bf2f(v[2]) * scale + shift, bf2f(v[3]) * scale + shift };
            f32x4 hi = { bf2f(v[4]) * scale + shift, bf2f(v[5]) * scale + shift,
                         bf2f(v[6]) * scale + shift, bf2f(v[7]) * scale + shift };
            *(f32x4*)o       = lo;
            *(f32x4*)(o + 4) = hi;
        }
    }
}

// ---------------------------------------------------------------- fallback (no big workspace; fp32 staging, 2-pass)
template <int PASS>
__global__ __launch_bounds__(256) void gram_bn_fb(
    const float* __restrict__ x, const float* __restrict__ w,
    const float* __restrict__ gamma, const float* __restrict__ beta,
    float* __restrict__ out, float* __restrict__ stats)
{
    const int tile = blockIdx.x;
    const int b    = blockIdx.y;
    const int c    = blockIdx.z;
    const int n    = b * NCH + c;
    const int tid  = threadIdx.x;

    float mean = 0.f, rstd = 0.f, gm = 0.f, bt = 0.f;
    if (PASS == 1) {
        float s  = stats[2*c];
        float sq = stats[2*c+1];
        mean = s * (1.0f / (float)NPC);
        float var = sq * (1.0f / (float)NPC) - mean * mean;
        rstd = rsqrtf(var + 1e-5f);
        gm = gamma[c]; bt = beta[c];
    }
    if (PASS == 1 && tile == 3) {
        float v = (0.f - mean) * rstd * gm + bt;
        f32x4 vv = {v, v, v, v};
        float* op = out + (size_t)n * PLANE_ELEMS;
        for (int it = 0; it < 16; ++it) {
            int t  = it * 256 + tid;
            int r  = t >> 5;
            int c4 = (t & 31) * 4;
            *(f32x4*)&op[(size_t)(128 + r) * HD + c4] = vv;
        }
        return;
    }
    int ti, tk;
    if      (tile == 0) { ti = 0; tk = 0; }
    else if (tile == 1) { ti = 0; tk = 1; }
    else                { ti = 1; tk = 1; }
    const float* xp = x + (size_t)n * PLANE_ELEMS;
    __shared__ short As[128 * 40];
    __shared__ short Bs[128 * 40];
    __shared__ float red[512];
    const int wid   = tid >> 6;
    const int lane  = tid & 63;
    const int waveM = wid >> 1, waveN = wid & 1;
    const int lrow  = lane & 15;
    const int lkk   = (lane >> 4) * 8;
    f32x4 acc[4][4];
    for (int i = 0; i < 4; ++i)
        for (int j = 0; j < 4; ++j)
            acc[i][j] = (f32x4){0.f, 0.f, 0.f, 0.f};
    const int rr = tid >> 3;
    const int cc = (tid & 7) * 4;
    for (int kb = 0; kb < 8; ++kb) {
        for (int it = 0; it < 4; ++it) {
            int r = rr + it * 32;
            f32x4 av = *(const f32x4*)&xp[(size_t)(ti*128 + r) * HD + kb*32 + cc];
            f32x4 bv = *(const f32x4*)&xp[(size_t)(tk*128 + r) * HD + kb*32 + cc];
            s16x4 a4 = { f2bf(av.x), f2bf(av.y), f2bf(av.z), f2bf(av.w) };
            s16x4 b4 = { f2bf(bv.x), f2bf(bv.y), f2bf(bv.z), f2bf(bv.w) };
            *(s16x4*)&As[r*40 + cc] = a4;
            *(s16x4*)&Bs[r*40 + cc] = b4;
        }
        __syncthreads();
        s16x8 af[4], bfr[4];
        for (int mi = 0; mi < 4; ++mi)
            af[mi]  = *(s16x8*)&As[(waveM*64 + mi*16 + lrow)*40 + lkk];
        for (int ni = 0; ni < 4; ++ni)
            bfr[ni] = *(s16x8*)&Bs[(waveN*64 + ni*16 + lrow)*40 + lkk];
        for (int mi = 0; mi < 4; ++mi)
            for (int ni = 0; ni < 4; ++ni)
                acc[mi][ni] = __builtin_amdgcn_mfma_f32_16x16x32_bf16(
                    af[mi], bfr[ni], acc[mi][ni], 0, 0, 0);
        __syncthreads();
    }
    float lsum = 0.f, lsq = 0.f;
    const int row0 = (lane >> 4) * 4;
    const int col0 = lane & 15;
    for (int mi = 0; mi < 4; ++mi) {
        for (int ni = 0; ni < 4; ++ni) {
            int gk = tk*128 + waveN*64 + ni*16 + col0;
            for (int r = 0; r < 4; ++r) {
                int gi = ti*128 + waveM*64 + mi*16 + row0 + r;
                float v = acc[mi][ni][r];
                float val = (gk >= gi)
                    ? v * w[(size_t)c * PLANE_ELEMS + (size_t)gi * HD + gk]
                    : 0.f;
                if (PASS == 0) { lsum += val; lsq += val * val; }
                else out[(size_t)n * PLANE_ELEMS + (size_t)gi * HD + gk] =
                        (val - mean) * rstd * gm + bt;
            }
        }
    }
    if (PASS == 0) {
        red[tid] = lsum; red[256 + tid] = lsq;
        __syncthreads();
        for (int s = 128; s > 0; s >>= 1) {
            if (tid < s) { red[tid] += red[tid+s]; red[256+tid] += red[256+tid+s]; }
            __syncthreads();
        }
        if (tid == 0) {
            atomicAdd(&stats[2*c],     red[0]);
            atomicAdd(&stats[2*c + 1], red[256]);
        }
    }
}

extern "C" void kernel_launch(void* const* d_in, const int* in_sizes, int n_in,
                              void* d_out, int out_size, void* d_ws, size_t ws_size,
                              hipStream_t stream) {
    const float* x     = (const float*)d_in[0];
    const float* w     = (const float*)d_in[1];
    const float* gamma = (const float*)d_in[2];
    const float* beta  = (const float*)d_in[3];
    float* out   = (float*)d_out;
    float* stats = (float*)d_ws;

    hipMemsetAsync(d_ws, 0, 128 * sizeof(float), stream);

    const size_t raw_bytes = (size_t)NPLANE * PLANE_ELEMS * sizeof(short); // 128 MiB
    if (ws_size >= 1024 + raw_bytes) {
        short* raw = (short*)((char*)d_ws + 1024);
        gram_kernel<<<dim3(10240), dim3(256), 0, stream>>>(x, w, raw, stats);
        bn_kernel<<<dim3(NPLANE, 16), dim3(256), 0, stream>>>(gamma, beta, out, stats, raw);
    } else {
        gram_bn_fb<0><<<dim3(3, NB, NCH), dim3(256), 0, stream>>>(x, w, gamma, beta, out, stats);
        gram_bn_fb<1><<<dim3(4, NB, NCH), dim3(256), 0, stream>>>(x, w, gamma, beta, out, stats);
    }
}